// Round 7
// baseline (2182.149 us; speedup 1.0000x reference)
//
#include <hip/hip_runtime.h>
#include <hip/hip_bf16.h>
#include <math.h>

// Problem constants (from reference)
#define B_SZ 128
#define T_SZ 65536
#define F_FR 4095          // (T - 32)/16 + 1
#define NSEQ (B_SZ * F_FR) // 524160
#define HID 8
#define CHUNK 256          // fast-scan chunk length
#define NCH (T_SZ / CHUNK) // 256 chunks

typedef _Float16 half8  __attribute__((ext_vector_type(8)));
typedef _Float16 half4v __attribute__((ext_vector_type(4)));
typedef __fp16   fp16x2 __attribute__((ext_vector_type(2)));   // cvt_pkrtz return type
typedef float    f32x4  __attribute__((ext_vector_type(4)));

#define L2E 1.4426950408889634f

static __device__ __forceinline__ float frcp(float v) {
#if __has_builtin(__builtin_amdgcn_rcpf)
    return __builtin_amdgcn_rcpf(v);
#else
    return 1.0f / v;
#endif
}
static __device__ __forceinline__ float fexp2(float v) {
#if __has_builtin(__builtin_amdgcn_exp2f)
    return __builtin_amdgcn_exp2f(v);
#else
    return exp2f(v);
#endif
}
__device__ __forceinline__ float sigm(float xv) { return frcp(1.0f + fexp2(-L2E * xv)); }

#define HSTR 72    // H row stride in f16 (144B: 16B-aligned for b128; 2-way banks)
#define XTSTR 68   // x^T row stride in f16 (136B: 8B-aligned b64; broadcast reads)

// ---------------- Pass 1: per-frame GRU via MFMA ----------------
// Round-7 = round-6 design with the cvt_pkrtz type fix (__fp16 vec2 return).
// r5 counters said VALU-per-MFMA was the wall:
//  * SINGLE-PLANE f16 H for MFMA input (f32 state stays in ho regs).
//    Halves MFMA count and A-frag reads; kills the 128-instr hi/lo prep.
//    Error budget: W.(h - f16(h)) ~1e-4/gate/step, contractive -> ~1e-3 y.
//  * M=64 seqs/wave (4 M-tiles share each W-frag read): 24KB W stream
//    amortized 2x.
//  * K-PERMUTE sigma(p)=(p&3)*16+(p>>2) applied to BOTH H cols and W's
//    k-dim (dot invariant under shared k-permute): lane's 4 h-updates
//    (m=0..3 at phys col 4*c16+m) become 4 CONTIGUOUS f16 -> cvt_pkrtz
//    pack + ds_write_b64 x16/step (2-way banks) vs 64 scalar b16 (4-way).
//  * x transposed [t][seq] f16 in LDS -> 4 broadcast ds_read_b64/step;
//    x*w_ih folded into the MFMA C-operand seed.
// Math identical otherwise: W rows pre-scaled -L2E (R/Z), 2*L2E (N);
// b_hh_n seeded INSIDE the r-product; C/D layout col=lane&15,row=4g+r.
__global__ __launch_bounds__(256, 2)
void gru_mfma(
    const float* __restrict__ x, const float* __restrict__ w_ih,
    const float* __restrict__ w_hh, const float* __restrict__ b_ih,
    const float* __restrict__ b_hh, const float* __restrict__ w_sl,
    const float* __restrict__ b_sl, float* __restrict__ ag)
{
    __shared__ _Float16 wlds[24 * 64 * 8];        // 24.0 KB frag-major W
    __shared__ _Float16 hlds[4][64 * HSTR];       // 36.0 KB (9 KB/wave)
    __shared__ _Float16 xlds[4][32 * XTSTR];      // 17.0 KB (x^T per wave)
    const int tid  = threadIdx.x;
    const int wv   = tid >> 6;
    const int lane = tid & 63;
    const int c16  = lane & 15;   // B-col (gate-in-tile) / A-row (seq-in-Mtile)
    const int g    = lane >> 4;   // k-group / C row-group
    _Float16* hb = &hlds[wv][0];
    _Float16* xw = &xlds[wv][0];
    const int tile = ((int)blockIdx.x * 4 + wv) * 64;   // 64 seqs per wave

    // ---- cooperative W stage (sigma k-permuted), 6 frags per wave ----
#pragma unroll
    for (int f = 0; f < 24; f += 4) {
        const int fi = f + wv;
        const int n = fi >> 1, c = fi & 1;
        const float sc = (n < 8) ? -L2E : (2.0f * L2E);
        const float* wr = w_hh + (16 * n + c16) * 64 + 8 * c + 2 * g;
        half8 w8;
#pragma unroll
        for (int e = 0; e < 8; ++e)                  // logical k = sigma(32c+8g+e)
            w8[e] = (_Float16)(sc * wr[(e & 3) * 16 + (e >> 2)]);
        *(half8*)(wlds + fi * 512 + lane * 8) = w8;
    }

    // ---- per-lane gate constants (gates j = c16 + 16m) ----
    float wiR[4], wiZ[4], wiN[4], bR[4], bZ[4], biN[4], bhN[4];
#pragma unroll
    for (int m = 0; m < 4; ++m) {
        const int j = c16 + 16 * m;
        wiR[m] = -L2E * w_ih[j];
        wiZ[m] = -L2E * w_ih[64 + j];
        wiN[m] = 2.0f * L2E * w_ih[128 + j];
        bR[m]  = -L2E * (b_ih[j] + b_hh[j]);
        bZ[m]  = -L2E * (b_ih[64 + j] + b_hh[64 + j]);
        biN[m] = 2.0f * L2E * b_ih[128 + j];          // additive part only
        bhN[m] = 2.0f * L2E * b_hh[128 + j];          // inside r-product (seeded)
    }

    // ---- stage x^T[32 t][64 seq] f16; zero H ----
    {
        int sq = tile + lane; if (sq > NSEQ - 1) sq = NSEQ - 1;  // tail clamp
        const int b = sq / F_FR, fr = sq % F_FR;
        const float* xp = x + (long)b * T_SZ + fr * 16;
#pragma unroll
        for (int t4 = 0; t4 < 32; t4 += 4) {
            const float4 q = *(const float4*)(xp + t4);
            xw[(t4 + 0) * XTSTR + lane] = (_Float16)q.x;
            xw[(t4 + 1) * XTSTR + lane] = (_Float16)q.y;
            xw[(t4 + 2) * XTSTR + lane] = (_Float16)q.z;
            xw[(t4 + 3) * XTSTR + lane] = (_Float16)q.w;
        }
    }
    {
        uint32_t* hz = (uint32_t*)hb;                 // 64*72/2 = 2304 dwords
#pragma unroll
        for (int i = 0; i < 36; ++i) hz[lane + 64 * i] = 0;
    }
    __syncthreads();   // wlds is cross-wave; H/X are per-wave

    float ho[4][4][4];   // [m][mt][r] f32 state
#pragma unroll
    for (int m = 0; m < 4; ++m)
#pragma unroll
        for (int mt = 0; mt < 4; ++mt)
#pragma unroll
            for (int r = 0; r < 4; ++r) ho[m][mt][r] = 0.0f;

#pragma unroll 1
    for (int t = 0; t < 32; ++t) {
        // A-frags (f16 H), 4 M-tiles x 2 k-chunks
        half8 ah[4][2];
#pragma unroll
        for (int mt = 0; mt < 4; ++mt)
#pragma unroll
            for (int c = 0; c < 2; ++c)
                ah[mt][c] = *(const half8*)(hb + (c16 + 16 * mt) * HSTR + 32 * c + 8 * g);
        // x_t (broadcast b64 reads), cvt to f32
        float xt[4][4];
#pragma unroll
        for (int mt = 0; mt < 4; ++mt) {
            const half4v xv = *(const half4v*)(xw + t * XTSTR + 16 * mt + 4 * g);
#pragma unroll
            for (int r = 0; r < 4; ++r) xt[mt][r] = (float)xv[r];
        }

        // m-interleaved: seeds -> 24 MFMAs -> elementwise, retire acc
#pragma unroll
        for (int m = 0; m < 4; ++m) {
            f32x4 aR[4], aZ[4], aN[4];
#pragma unroll
            for (int mt = 0; mt < 4; ++mt)
#pragma unroll
                for (int r = 0; r < 4; ++r) {
                    aR[mt][r] = fmaf(xt[mt][r], wiR[m], bR[m]);   // x folded in seed
                    aZ[mt][r] = fmaf(xt[mt][r], wiZ[m], bZ[m]);
                    aN[mt][r] = bhN[m];
                }
#pragma unroll
            for (int c = 0; c < 2; ++c) {
                const half8 bfR = *(const half8*)(wlds + (2 * m + c)       * 512 + lane * 8);
                const half8 bfZ = *(const half8*)(wlds + (2 * (4 + m) + c) * 512 + lane * 8);
                const half8 bfN = *(const half8*)(wlds + (2 * (8 + m) + c) * 512 + lane * 8);
#pragma unroll
                for (int mt = 0; mt < 4; ++mt) {
                    aR[mt] = __builtin_amdgcn_mfma_f32_16x16x32_f16(ah[mt][c], bfR, aR[mt], 0, 0, 0);
                    aZ[mt] = __builtin_amdgcn_mfma_f32_16x16x32_f16(ah[mt][c], bfZ, aZ[mt], 0, 0, 0);
                    aN[mt] = __builtin_amdgcn_mfma_f32_16x16x32_f16(ah[mt][c], bfN, aN[mt], 0, 0, 0);
                }
            }
#pragma unroll
            for (int mt = 0; mt < 4; ++mt)
#pragma unroll
                for (int r = 0; r < 4; ++r) {
                    const float rr = frcp(1.0f + fexp2(aR[mt][r]));       // sigmoid
                    const float zf = frcp(1.0f + fexp2(aZ[mt][r]));       // sigmoid
                    const float uN = fmaf(rr, aN[mt][r], fmaf(xt[mt][r], wiN[m], biN[m]));
                    const float nn = fmaf(-2.0f, frcp(1.0f + fexp2(uN)), 1.0f); // tanh
                    ho[m][mt][r] = fmaf(zf, ho[m][mt][r] - nn, nn);
                }
        }

        // H write-back: pack m=0..3 (phys cols 4c16..4c16+3 contiguous) -> b64
#pragma unroll
        for (int mt = 0; mt < 4; ++mt)
#pragma unroll
            for (int r = 0; r < 4; ++r) {
                const fp16x2 p0 = __builtin_amdgcn_cvt_pkrtz(ho[0][mt][r], ho[1][mt][r]);
                const fp16x2 p1 = __builtin_amdgcn_cvt_pkrtz(ho[2][mt][r], ho[3][mt][r]);
                half4v hv;
                hv.x = (_Float16)p0.x; hv.y = (_Float16)p0.y;
                hv.z = (_Float16)p1.x; hv.w = (_Float16)p1.y;
                *(half4v*)(hb + (4 * g + r + 16 * mt) * HSTR + 4 * c16) = hv;
            }
    }

    // ---- epilogue: eps = hT @ w_sl^T + b_sl (sigma-gathered w_sl) ----
    half8 wsl[2];
#pragma unroll
    for (int c = 0; c < 2; ++c) {
        const float* wr = w_sl + c16 * 64 + 8 * c + 2 * g;
#pragma unroll
        for (int e = 0; e < 8; ++e) wsl[c][e] = (_Float16)wr[(e & 3) * 16 + (e >> 2)];
    }
    const float bs = b_sl[c16];
    const f32x4 zz = {0.0f, 0.0f, 0.0f, 0.0f};
#pragma unroll
    for (int mt = 0; mt < 4; ++mt) {
        const half8 fh0 = *(const half8*)(hb + (c16 + 16 * mt) * HSTR + 8 * g);
        const half8 fh1 = *(const half8*)(hb + (c16 + 16 * mt) * HSTR + 32 + 8 * g);
        f32x4 ec = __builtin_amdgcn_mfma_f32_16x16x32_f16(fh0, wsl[0], zz, 0, 0, 0);
        ec = __builtin_amdgcn_mfma_f32_16x16x32_f16(fh1, wsl[1], ec, 0, 0, 0);
#pragma unroll
        for (int r = 0; r < 4; ++r) {
            const int s = tile + 16 * mt + 4 * g + r;
            if (s < NSEQ) {
                float e = ec[r] + bs;
                if (c16 < 8) e = sigm(e);    // A_s = sigmoid(eps[:8]); g_s raw
                ag[(long)s * 16 + c16] = e;
            }
        }
    }
}

// ---------------- Pass 2a: fast-scan chunk summaries ----------------
__global__ __launch_bounds__(256) void fast_chunk(
    const float* __restrict__ x, const float* __restrict__ ag,
    const float* __restrict__ w_in,
    float* __restrict__ chP, float* __restrict__ chH)
{
    const int tid = blockIdx.x * 256 + threadIdx.x;  // tid = b*NCH + c
    const int b = tid / NCH, c = tid % NCH;
    float h[HID], P[HID];
#pragma unroll
    for (int i = 0; i < HID; ++i) { h[i] = 0.0f; P[i] = 1.0f; }
    const float* xp = x + (long)b * T_SZ + c * CHUNK;

#pragma unroll 1
    for (int g = 0; g < CHUNK / 16; ++g) {
        const int t0 = c * CHUNK + g * 16;
        int fr = t0 / 16 - 1; fr = max(0, min(F_FR - 1, fr));
        const float4* agp = (const float4*)(ag + ((long)b * F_FR + fr) * 16);
        const float4 a0 = agp[0], a1 = agp[1], g0 = agp[2], g1 = agp[3];
        const float A[HID]  = {a0.x, a0.y, a0.z, a0.w, a1.x, a1.y, a1.z, a1.w};
        const float Gv[HID] = {g0.x, g0.y, g0.z, g0.w, g1.x, g1.y, g1.z, g1.w};
        float wg[HID];
#pragma unroll
        for (int i = 0; i < HID; ++i) wg[i] = w_in[i] * Gv[i];
#pragma unroll
        for (int tt = 0; tt < 16; ++tt) {
            const float xt = xp[g * 16 + tt];
#pragma unroll
            for (int i = 0; i < HID; ++i) h[i] = fmaf(A[i], h[i], xt * wg[i]);
        }
#pragma unroll
        for (int i = 0; i < HID; ++i) {
            const float a2 = A[i] * A[i]; const float a4 = a2 * a2; const float a8 = a4 * a4;
            P[i] *= a8 * a8;
        }
    }
    float* pp = chP + (long)tid * HID;
    float* hp = chH + (long)tid * HID;
#pragma unroll
    for (int i = 0; i < HID; ++i) { pp[i] = P[i]; hp[i] = h[i]; }
}

// ---------------- Pass 2b: scan over chunks ----------------
__global__ __launch_bounds__(256) void chunk_scan(
    const float* __restrict__ chP, const float* __restrict__ chH,
    float* __restrict__ st)
{
    const int tid = blockIdx.x * 256 + threadIdx.x;
    if (tid >= B_SZ * HID) return;
    const int b = tid / HID, i = tid % HID;
    float h = 0.0f;
#pragma unroll 1
    for (int c = 0; c < NCH; ++c) {
        const long idx = ((long)b * NCH + c) * HID + i;
        st[idx] = h;
        h = fmaf(chP[idx], h, chH[idx]);
    }
}

// ---------------- Pass 2c: apply + output ----------------
__global__ __launch_bounds__(256) void fast_apply(
    const float* __restrict__ x, const float* __restrict__ ag,
    const float* __restrict__ w_in, const float* __restrict__ w_out,
    const float* __restrict__ st, float* __restrict__ y)
{
    const int tid = blockIdx.x * 256 + threadIdx.x;  // tid = b*NCH + c
    const int b = tid / NCH, c = tid % NCH;
    float h[HID];
    const float* sp = st + (long)tid * HID;
#pragma unroll
    for (int i = 0; i < HID; ++i) h[i] = sp[i];
    float wo[HID];
#pragma unroll
    for (int i = 0; i < HID; ++i) wo[i] = w_out[i];
    const float* xp = x + (long)b * T_SZ + c * CHUNK;
    float* yp = y + (long)b * T_SZ + c * CHUNK;

#pragma unroll 1
    for (int g = 0; g < CHUNK / 16; ++g) {
        const int t0 = c * CHUNK + g * 16;
        int fr = t0 / 16 - 1; fr = max(0, min(F_FR - 1, fr));
        const float4* agp = (const float4*)(ag + ((long)b * F_FR + fr) * 16);
        const float4 a0 = agp[0], a1 = agp[1], g0 = agp[2], g1 = agp[3];
        const float A[HID]  = {a0.x, a0.y, a0.z, a0.w, a1.x, a1.y, a1.z, a1.w};
        const float Gv[HID] = {g0.x, g0.y, g0.z, g0.w, g1.x, g1.y, g1.z, g1.w};
        float wg[HID];
#pragma unroll
        for (int i = 0; i < HID; ++i) wg[i] = w_in[i] * Gv[i];
#pragma unroll
        for (int tt = 0; tt < 16; ++tt) {
            const float xt = xp[g * 16 + tt];
            float acc = 0.0f;
#pragma unroll
            for (int i = 0; i < HID; ++i) {
                h[i] = fmaf(A[i], h[i], xt * wg[i]);
                acc = fmaf(h[i], wo[i], acc);
            }
            yp[g * 16 + tt] = acc;
        }
    }
}

extern "C" void kernel_launch(void* const* d_in, const int* in_sizes, int n_in,
                              void* d_out, int out_size, void* d_ws, size_t ws_size,
                              hipStream_t stream) {
    const float* x    = (const float*)d_in[0];
    const float* w_in = (const float*)d_in[1];
    const float* w_out= (const float*)d_in[2];
    const float* w_ih = (const float*)d_in[3];
    const float* w_hh = (const float*)d_in[4];
    const float* b_ih = (const float*)d_in[5];
    const float* b_hh = (const float*)d_in[6];
    const float* w_sl = (const float*)d_in[7];
    const float* b_sl = (const float*)d_in[8];
    float* y = (float*)d_out;

    // Workspace layout (floats): ag[B][F][16] | chP[B][NCH][8] | chH | st
    float* ag  = (float*)d_ws;
    size_t off = (size_t)B_SZ * F_FR * 16;            // 8,386,560
    float* chP = ag + off;
    float* chH = chP + (size_t)B_SZ * NCH * HID;      // 262,144 each
    float* st  = chH + (size_t)B_SZ * NCH * HID;      // total ~36.7 MB

    // 524,160 seqs; 2048 blocks x 4 waves x 64 seqs (last 2 waves tail-guarded)
    gru_mfma<<<2048, 256, 0, stream>>>(x, w_ih, w_hh, b_ih, b_hh, w_sl, b_sl, ag);
    fast_chunk<<<(B_SZ * NCH) / 256, 256, 0, stream>>>(x, ag, w_in, chP, chH);
    chunk_scan<<<(B_SZ * HID + 255) / 256, 256, 0, stream>>>(chP, chH, st);
    fast_apply<<<(B_SZ * NCH) / 256, 256, 0, stream>>>(x, ag, w_in, w_out, st, y);
}

// Round 8
// 1192.905 us; speedup vs baseline: 1.8293x; 1.8293x over previous
//
#include <hip/hip_runtime.h>
#include <hip/hip_bf16.h>
#include <math.h>

// Problem constants (from reference)
#define B_SZ 128
#define T_SZ 65536
#define F_FR 4095          // (T - 32)/16 + 1
#define NSEQ (B_SZ * F_FR) // 524160 = 4095 blocks * 128 seqs (exact, no tail)
#define HID 8
#define CHUNK 256          // fast-scan chunk length
#define NCH (T_SZ / CHUNK) // 256 chunks

typedef _Float16 half8  __attribute__((ext_vector_type(8)));
typedef _Float16 half4v __attribute__((ext_vector_type(4)));
typedef __fp16   fp16x2 __attribute__((ext_vector_type(2)));   // cvt_pkrtz return type
typedef float    f32x4  __attribute__((ext_vector_type(4)));

#define L2E 1.4426950408889634f

static __device__ __forceinline__ float frcp(float v) {
#if __has_builtin(__builtin_amdgcn_rcpf)
    return __builtin_amdgcn_rcpf(v);
#else
    return 1.0f / v;
#endif
}
static __device__ __forceinline__ float fexp2(float v) {
#if __has_builtin(__builtin_amdgcn_exp2f)
    return __builtin_amdgcn_exp2f(v);
#else
    return exp2f(v);
#endif
}
__device__ __forceinline__ float sigm(float xv) { return frcp(1.0f + fexp2(-L2E * xv)); }

#define HSTR 72    // H row stride in f16 (144B: 16B-aligned for b128; 2-way banks)
#define XTSTR 36   // x^T row stride in f16 (72B; broadcast b64 reads)

// ---------------- Pass 1: per-frame GRU via MFMA ----------------
// Round-8: r7 design scaled back to M=32 seqs/wave. r7's M=64 needed ~200
// live VGPRs; the allocator capped at 128 and spilled ho[64] -> 8 GB of
// scratch HBM traffic (FETCH 5.2 GB, MfmaUtil 8.6%). M=32 halves the f32
// state (ho=32) and live accs (24) -> ~134 peak live, the r5-proven
// no-spill regime. Kept from r7:
//  * SINGLE-PLANE f16 H for MFMA input (f32 state in ho regs; only
//    W.(h - f16(h)) ~1e-4/step enters -> ~1e-3 y, passed r7).
//  * K-PERMUTE sigma(p)=(p&3)*16+(p>>2) on BOTH H cols and W k-dim ->
//    lane's 4 h-updates contiguous -> cvt_pkrtz + ds_write_b64 x8/step.
//  * x^T [t][seq] f16 in LDS; x*w_ih folded into MFMA C-seed.
//  * m-interleave (retire 24-reg acc per gate block); biases seeded in C
//    (b_hh_n INSIDE the r-product).
// W rows pre-scaled -L2E (R/Z), 2*L2E (N); C/D layout col=lane&15, row=4g+r.
__global__ __launch_bounds__(256)
void gru_mfma(
    const float* __restrict__ x, const float* __restrict__ w_ih,
    const float* __restrict__ w_hh, const float* __restrict__ b_ih,
    const float* __restrict__ b_hh, const float* __restrict__ w_sl,
    const float* __restrict__ b_sl, float* __restrict__ ag)
{
    __shared__ _Float16 wlds[24 * 64 * 8];        // 24.0 KB frag-major W
    __shared__ _Float16 hlds[4][32 * HSTR];       // 18.0 KB (4.5 KB/wave)
    __shared__ _Float16 xlds[4][32 * XTSTR];      // 9.0 KB (x^T per wave)
    const int tid  = threadIdx.x;
    const int wv   = tid >> 6;
    const int lane = tid & 63;
    const int c16  = lane & 15;   // B-col (gate-in-tile) / A-row (seq-in-Mtile)
    const int g    = lane >> 4;   // k-group / C row-group
    _Float16* hb = &hlds[wv][0];
    _Float16* xw = &xlds[wv][0];
    const int tile = ((int)blockIdx.x * 4 + wv) * 32;   // 32 seqs per wave

    // ---- cooperative W stage (sigma k-permuted), 6 frags per wave ----
#pragma unroll
    for (int f = 0; f < 24; f += 4) {
        const int fi = f + wv;
        const int n = fi >> 1, c = fi & 1;
        const float sc = (n < 8) ? -L2E : (2.0f * L2E);
        const float* wr = w_hh + (16 * n + c16) * 64 + 8 * c + 2 * g;
        half8 w8;
#pragma unroll
        for (int e = 0; e < 8; ++e)                  // logical k = sigma(32c+8g+e)
            w8[e] = (_Float16)(sc * wr[(e & 3) * 16 + (e >> 2)]);
        *(half8*)(wlds + fi * 512 + lane * 8) = w8;
    }

    // ---- per-lane gate constants (gates j = c16 + 16m) ----
    float wiR[4], wiZ[4], wiN[4], bR[4], bZ[4], biN[4], bhN[4];
#pragma unroll
    for (int m = 0; m < 4; ++m) {
        const int j = c16 + 16 * m;
        wiR[m] = -L2E * w_ih[j];
        wiZ[m] = -L2E * w_ih[64 + j];
        wiN[m] = 2.0f * L2E * w_ih[128 + j];
        bR[m]  = -L2E * (b_ih[j] + b_hh[j]);
        bZ[m]  = -L2E * (b_ih[64 + j] + b_hh[64 + j]);
        biN[m] = 2.0f * L2E * b_ih[128 + j];          // additive part only
        bhN[m] = 2.0f * L2E * b_hh[128 + j];          // inside r-product (seeded)
    }

    // ---- stage x^T[32 t][32 seq] f16 (each lane: 16 t of one seq); zero H ----
    {
        const int sl = lane & 31, hf = lane >> 5;
        const int sq = tile + sl;
        const int b = sq / F_FR, fr = sq % F_FR;
        const float* xp = x + (long)b * T_SZ + fr * 16 + 16 * hf;
#pragma unroll
        for (int t4 = 0; t4 < 16; t4 += 4) {
            const float4 q = *(const float4*)(xp + t4);
            xw[(16 * hf + t4 + 0) * XTSTR + sl] = (_Float16)q.x;
            xw[(16 * hf + t4 + 1) * XTSTR + sl] = (_Float16)q.y;
            xw[(16 * hf + t4 + 2) * XTSTR + sl] = (_Float16)q.z;
            xw[(16 * hf + t4 + 3) * XTSTR + sl] = (_Float16)q.w;
        }
    }
    {
        uint32_t* hz = (uint32_t*)hb;                 // 32*72/2 = 1152 dwords
#pragma unroll
        for (int i = 0; i < 18; ++i) hz[lane + 64 * i] = 0;
    }
    __syncthreads();   // wlds is cross-wave; H/X are per-wave

    float ho[4][2][4];   // [m][mt][r] f32 state (32 regs)
#pragma unroll
    for (int m = 0; m < 4; ++m)
#pragma unroll
        for (int mt = 0; mt < 2; ++mt)
#pragma unroll
            for (int r = 0; r < 4; ++r) ho[m][mt][r] = 0.0f;

#pragma unroll 1
    for (int t = 0; t < 32; ++t) {
        // A-frags (f16 H), 2 M-tiles x 2 k-chunks
        half8 ah[2][2];
#pragma unroll
        for (int mt = 0; mt < 2; ++mt)
#pragma unroll
            for (int c = 0; c < 2; ++c)
                ah[mt][c] = *(const half8*)(hb + (c16 + 16 * mt) * HSTR + 32 * c + 8 * g);
        // x_t (broadcast b64 reads), cvt to f32
        float xt[2][4];
#pragma unroll
        for (int mt = 0; mt < 2; ++mt) {
            const half4v xv = *(const half4v*)(xw + t * XTSTR + 16 * mt + 4 * g);
#pragma unroll
            for (int r = 0; r < 4; ++r) xt[mt][r] = (float)xv[r];
        }

        // m-interleaved: seeds -> 12 MFMAs per block -> elementwise, retire acc
#pragma unroll
        for (int m = 0; m < 4; ++m) {
            f32x4 aR[2], aZ[2], aN[2];
#pragma unroll
            for (int mt = 0; mt < 2; ++mt)
#pragma unroll
                for (int r = 0; r < 4; ++r) {
                    aR[mt][r] = fmaf(xt[mt][r], wiR[m], bR[m]);   // x folded in seed
                    aZ[mt][r] = fmaf(xt[mt][r], wiZ[m], bZ[m]);
                    aN[mt][r] = bhN[m];
                }
#pragma unroll
            for (int c = 0; c < 2; ++c) {
                const half8 bfR = *(const half8*)(wlds + (2 * m + c)       * 512 + lane * 8);
                const half8 bfZ = *(const half8*)(wlds + (2 * (4 + m) + c) * 512 + lane * 8);
                const half8 bfN = *(const half8*)(wlds + (2 * (8 + m) + c) * 512 + lane * 8);
#pragma unroll
                for (int mt = 0; mt < 2; ++mt) {
                    aR[mt] = __builtin_amdgcn_mfma_f32_16x16x32_f16(ah[mt][c], bfR, aR[mt], 0, 0, 0);
                    aZ[mt] = __builtin_amdgcn_mfma_f32_16x16x32_f16(ah[mt][c], bfZ, aZ[mt], 0, 0, 0);
                    aN[mt] = __builtin_amdgcn_mfma_f32_16x16x32_f16(ah[mt][c], bfN, aN[mt], 0, 0, 0);
                }
            }
#pragma unroll
            for (int mt = 0; mt < 2; ++mt)
#pragma unroll
                for (int r = 0; r < 4; ++r) {
                    const float rr = frcp(1.0f + fexp2(aR[mt][r]));       // sigmoid
                    const float zf = frcp(1.0f + fexp2(aZ[mt][r]));       // sigmoid
                    const float uN = fmaf(rr, aN[mt][r], fmaf(xt[mt][r], wiN[m], biN[m]));
                    const float nn = fmaf(-2.0f, frcp(1.0f + fexp2(uN)), 1.0f); // tanh
                    ho[m][mt][r] = fmaf(zf, ho[m][mt][r] - nn, nn);
                }
        }

        // H write-back: pack m=0..3 (phys cols 4c16..4c16+3 contiguous) -> b64
#pragma unroll
        for (int mt = 0; mt < 2; ++mt)
#pragma unroll
            for (int r = 0; r < 4; ++r) {
                const fp16x2 p0 = __builtin_amdgcn_cvt_pkrtz(ho[0][mt][r], ho[1][mt][r]);
                const fp16x2 p1 = __builtin_amdgcn_cvt_pkrtz(ho[2][mt][r], ho[3][mt][r]);
                half4v hv;
                hv.x = (_Float16)p0.x; hv.y = (_Float16)p0.y;
                hv.z = (_Float16)p1.x; hv.w = (_Float16)p1.y;
                *(half4v*)(hb + (4 * g + r + 16 * mt) * HSTR + 4 * c16) = hv;
            }
    }

    // ---- epilogue: eps = hT @ w_sl^T + b_sl (sigma-gathered w_sl) ----
    half8 wsl[2];
#pragma unroll
    for (int c = 0; c < 2; ++c) {
        const float* wr = w_sl + c16 * 64 + 8 * c + 2 * g;
#pragma unroll
        for (int e = 0; e < 8; ++e) wsl[c][e] = (_Float16)wr[(e & 3) * 16 + (e >> 2)];
    }
    const float bs = b_sl[c16];
    const f32x4 zz = {0.0f, 0.0f, 0.0f, 0.0f};
#pragma unroll
    for (int mt = 0; mt < 2; ++mt) {
        const half8 fh0 = *(const half8*)(hb + (c16 + 16 * mt) * HSTR + 8 * g);
        const half8 fh1 = *(const half8*)(hb + (c16 + 16 * mt) * HSTR + 32 + 8 * g);
        f32x4 ec = __builtin_amdgcn_mfma_f32_16x16x32_f16(fh0, wsl[0], zz, 0, 0, 0);
        ec = __builtin_amdgcn_mfma_f32_16x16x32_f16(fh1, wsl[1], ec, 0, 0, 0);
#pragma unroll
        for (int r = 0; r < 4; ++r) {
            float e = ec[r] + bs;
            if (c16 < 8) e = sigm(e);    // A_s = sigmoid(eps[:8]); g_s raw
            ag[(long)(tile + 16 * mt + 4 * g + r) * 16 + c16] = e;
        }
    }
}

// ---------------- Pass 2a: fast-scan chunk summaries ----------------
__global__ __launch_bounds__(256) void fast_chunk(
    const float* __restrict__ x, const float* __restrict__ ag,
    const float* __restrict__ w_in,
    float* __restrict__ chP, float* __restrict__ chH)
{
    const int tid = blockIdx.x * 256 + threadIdx.x;  // tid = b*NCH + c
    const int b = tid / NCH, c = tid % NCH;
    float h[HID], P[HID];
#pragma unroll
    for (int i = 0; i < HID; ++i) { h[i] = 0.0f; P[i] = 1.0f; }
    const float* xp = x + (long)b * T_SZ + c * CHUNK;

#pragma unroll 1
    for (int g = 0; g < CHUNK / 16; ++g) {
        const int t0 = c * CHUNK + g * 16;
        int fr = t0 / 16 - 1; fr = max(0, min(F_FR - 1, fr));
        const float4* agp = (const float4*)(ag + ((long)b * F_FR + fr) * 16);
        const float4 a0 = agp[0], a1 = agp[1], g0 = agp[2], g1 = agp[3];
        const float A[HID]  = {a0.x, a0.y, a0.z, a0.w, a1.x, a1.y, a1.z, a1.w};
        const float Gv[HID] = {g0.x, g0.y, g0.z, g0.w, g1.x, g1.y, g1.z, g1.w};
        float wg[HID];
#pragma unroll
        for (int i = 0; i < HID; ++i) wg[i] = w_in[i] * Gv[i];
#pragma unroll
        for (int tt = 0; tt < 16; ++tt) {
            const float xt = xp[g * 16 + tt];
#pragma unroll
            for (int i = 0; i < HID; ++i) h[i] = fmaf(A[i], h[i], xt * wg[i]);
        }
#pragma unroll
        for (int i = 0; i < HID; ++i) {
            const float a2 = A[i] * A[i]; const float a4 = a2 * a2; const float a8 = a4 * a4;
            P[i] *= a8 * a8;
        }
    }
    float* pp = chP + (long)tid * HID;
    float* hp = chH + (long)tid * HID;
#pragma unroll
    for (int i = 0; i < HID; ++i) { pp[i] = P[i]; hp[i] = h[i]; }
}

// ---------------- Pass 2b: scan over chunks ----------------
__global__ __launch_bounds__(256) void chunk_scan(
    const float* __restrict__ chP, const float* __restrict__ chH,
    float* __restrict__ st)
{
    const int tid = blockIdx.x * 256 + threadIdx.x;
    if (tid >= B_SZ * HID) return;
    const int b = tid / HID, i = tid % HID;
    float h = 0.0f;
#pragma unroll 1
    for (int c = 0; c < NCH; ++c) {
        const long idx = ((long)b * NCH + c) * HID + i;
        st[idx] = h;
        h = fmaf(chP[idx], h, chH[idx]);
    }
}

// ---------------- Pass 2c: apply + output ----------------
__global__ __launch_bounds__(256) void fast_apply(
    const float* __restrict__ x, const float* __restrict__ ag,
    const float* __restrict__ w_in, const float* __restrict__ w_out,
    const float* __restrict__ st, float* __restrict__ y)
{
    const int tid = blockIdx.x * 256 + threadIdx.x;  // tid = b*NCH + c
    const int b = tid / NCH, c = tid % NCH;
    float h[HID];
    const float* sp = st + (long)tid * HID;
#pragma unroll
    for (int i = 0; i < HID; ++i) h[i] = sp[i];
    float wo[HID];
#pragma unroll
    for (int i = 0; i < HID; ++i) wo[i] = w_out[i];
    const float* xp = x + (long)b * T_SZ + c * CHUNK;
    float* yp = y + (long)b * T_SZ + c * CHUNK;

#pragma unroll 1
    for (int g = 0; g < CHUNK / 16; ++g) {
        const int t0 = c * CHUNK + g * 16;
        int fr = t0 / 16 - 1; fr = max(0, min(F_FR - 1, fr));
        const float4* agp = (const float4*)(ag + ((long)b * F_FR + fr) * 16);
        const float4 a0 = agp[0], a1 = agp[1], g0 = agp[2], g1 = agp[3];
        const float A[HID]  = {a0.x, a0.y, a0.z, a0.w, a1.x, a1.y, a1.z, a1.w};
        const float Gv[HID] = {g0.x, g0.y, g0.z, g0.w, g1.x, g1.y, g1.z, g1.w};
        float wg[HID];
#pragma unroll
        for (int i = 0; i < HID; ++i) wg[i] = w_in[i] * Gv[i];
#pragma unroll
        for (int tt = 0; tt < 16; ++tt) {
            const float xt = xp[g * 16 + tt];
            float acc = 0.0f;
#pragma unroll
            for (int i = 0; i < HID; ++i) {
                h[i] = fmaf(A[i], h[i], xt * wg[i]);
                acc = fmaf(h[i], wo[i], acc);
            }
            yp[g * 16 + tt] = acc;
        }
    }
}

extern "C" void kernel_launch(void* const* d_in, const int* in_sizes, int n_in,
                              void* d_out, int out_size, void* d_ws, size_t ws_size,
                              hipStream_t stream) {
    const float* x    = (const float*)d_in[0];
    const float* w_in = (const float*)d_in[1];
    const float* w_out= (const float*)d_in[2];
    const float* w_ih = (const float*)d_in[3];
    const float* w_hh = (const float*)d_in[4];
    const float* b_ih = (const float*)d_in[5];
    const float* b_hh = (const float*)d_in[6];
    const float* w_sl = (const float*)d_in[7];
    const float* b_sl = (const float*)d_in[8];
    float* y = (float*)d_out;

    // Workspace layout (floats): ag[B][F][16] | chP[B][NCH][8] | chH | st
    float* ag  = (float*)d_ws;
    size_t off = (size_t)B_SZ * F_FR * 16;            // 8,386,560
    float* chP = ag + off;
    float* chH = chP + (size_t)B_SZ * NCH * HID;      // 262,144 each
    float* st  = chH + (size_t)B_SZ * NCH * HID;      // total ~36.7 MB

    // 524,160 seqs = 4095 blocks x 4 waves x 32 seqs (exact)
    gru_mfma<<<4095, 256, 0, stream>>>(x, w_ih, w_hh, b_ih, b_hh, w_sl, b_sl, ag);
    fast_chunk<<<(B_SZ * NCH) / 256, 256, 0, stream>>>(x, ag, w_in, chP, chH);
    chunk_scan<<<(B_SZ * HID + 255) / 256, 256, 0, stream>>>(chP, chH, st);
    fast_apply<<<(B_SZ * NCH) / 256, 256, 0, stream>>>(x, ag, w_in, w_out, st, y);
}